// Round 7
// baseline (161.447 us; speedup 1.0000x reference)
//
#include <hip/hip_runtime.h>
#include <hip/hip_bf16.h>
#include <hip/hip_fp16.h>

// Sparse gather-FFN. R6 measured per CU: DS ~68us (41 base + 27 conflict,
// 7.9 extra cyc per wave ds_read_b128), VALU ~45us, dur 81us -> DS-bound.
// R7: conflict shaping. Dot over K=16 is commutative and indices are the
// same for every block, so the prepass stable-sorts each unit's 16
// (idx,w) slots by LDS bank group (f%8) and applies a lane-staggered
// cyclic phase -> at each gather step the wave's 64 lanes hit flattened
// group distributions (toward 8/group) instead of multinomial (max~13).
// Plus: approx-rcp sigmoid (v_rcp, no div fixup).

#define NB   32768
#define NIN  128
#define NL   8
#define NW   256
#define NK   16
#define RPB  8                        // batch rows per block (8 f16 = 16 B)
#define STORED (NIN + (NL - 1) * NW)  // 1920 features ever re-read
#define NPARAM (NL * NW * NK)         // 32768 (l,u,k) entries

typedef __fp16 fp16v2 __attribute__((ext_vector_type(2)));

__device__ __forceinline__ unsigned pk16(float a, float b) {
    fp16v2 p = __builtin_amdgcn_cvt_pkrtz(a, b);   // v_cvt_pkrtz_f16_f32
    return __builtin_bit_cast(unsigned, p);
}

__device__ __forceinline__ __half2 as_h2(unsigned u) {
    return __builtin_bit_cast(__half2, u);
}

__device__ __forceinline__ float fast_sigmoid(float x) {
    // v_mul + v_exp + v_add + v_rcp (approx; err ~1e-5 << bf16 floor)
    return __builtin_amdgcn_rcpf(1.0f + __expf(-x));
}

// 8 row-MACs from one 16B packed-f16 word: 4x v_pk_fma_f16
__device__ __forceinline__ void fma_feat(__half2 acc[4], __half2 w2, uint4 p) {
    acc[0] = __hfma2(as_h2(p.x), w2, acc[0]);
    acc[1] = __hfma2(as_h2(p.y), w2, acc[1]);
    acc[2] = __hfma2(as_h2(p.z), w2, acc[2]);
    acc[3] = __hfma2(as_h2(p.w), w2, acc[3]);
}

template <bool PRE>
__global__ __launch_bounds__(256, 5)
void ffn_gather_kernel(const float* __restrict__ inputs,
                       const float* __restrict__ weights,
                       const float* __restrict__ biases,
                       const int*   __restrict__ edge_idx,
                       const int*   __restrict__ idxb,   // pre-scaled byte offs
                       const unsigned* __restrict__ wpk, // packed (w,w) f16
                       float* __restrict__ out)
{
    __shared__ uint4 vals[STORED];   // vals[f] = 8 f16 rows of feature f

    const int t = threadIdx.x;                       // 0..255, unit id
    const long long row0 = (long long)blockIdx.x * RPB;
    const char* vbase = (const char*)vals;

    // ---- stage the 128 input features for 8 rows (feature-major, f16) ----
    if (t < NIN) {
        float v[RPB];
        #pragma unroll
        for (int r = 0; r < RPB; ++r) v[r] = inputs[(row0 + r) * NIN + t];
        uint4 p;
        p.x = pk16(v[0], v[1]);
        p.y = pk16(v[2], v[3]);
        p.z = pk16(v[4], v[5]);
        p.w = pk16(v[6], v[7]);
        vals[t] = p;
    }
    __syncthreads();

    // ---- layers ----
    #pragma unroll
    for (int l = 0; l < NL; ++l) {
        const int base = (l * NW + t) * NK;

        const float b = biases[l * NW + t];
        __half2 acc[4];
        const __half2 bb = __float2half2_rn(b);
        #pragma unroll
        for (int j = 0; j < 4; ++j) acc[j] = bb;

        #pragma unroll
        for (int kk = 0; kk < NK / 4; ++kk) {
            int4 o4;          // byte offsets into vals
            __half2 w0, w1, w2, w3;
            if (PRE) {
                o4 = ((const int4*)(idxb + base))[kk];
                uint4 wp = ((const uint4*)(wpk + base))[kk];
                w0 = as_h2(wp.x); w1 = as_h2(wp.y);
                w2 = as_h2(wp.z); w3 = as_h2(wp.w);
            } else {
                int4 i4 = ((const int4*)(edge_idx + base))[kk];
                o4.x = i4.x << 4; o4.y = i4.y << 4;
                o4.z = i4.z << 4; o4.w = i4.w << 4;
                float4 w4 = ((const float4*)(weights + base))[kk];
                w0 = __float2half2_rn(w4.x);
                w1 = __float2half2_rn(w4.y);
                w2 = __float2half2_rn(w4.z);
                w3 = __float2half2_rn(w4.w);
            }
            const uint4 p0 = *(const uint4*)(vbase + o4.x);
            const uint4 p1 = *(const uint4*)(vbase + o4.y);
            const uint4 p2 = *(const uint4*)(vbase + o4.z);
            const uint4 p3 = *(const uint4*)(vbase + o4.w);
            fma_feat(acc, w0, p0);
            fma_feat(acc, w1, p1);
            fma_feat(acc, w2, p2);
            fma_feat(acc, w3, p3);
        }

        float s[RPB];
        #pragma unroll
        for (int j = 0; j < 4; ++j) {
            s[2 * j + 0] = fast_sigmoid(__low2float(acc[j]));
            s[2 * j + 1] = fast_sigmoid(__high2float(acc[j]));
        }

        if (l < NL - 1) {
            // layer-l writes land above every layer-l read region -> no
            // pre-write sync needed; one barrier before next layer's reads.
            uint4 p;
            p.x = pk16(s[0], s[1]);
            p.y = pk16(s[2], s[3]);
            p.z = pk16(s[4], s[5]);
            p.w = pk16(s[6], s[7]);
            vals[NIN + l * NW + t] = p;
            __syncthreads();
        } else {
            // final layer: fp32 straight to out
            #pragma unroll
            for (int r = 0; r < RPB; ++r)
                out[(row0 + r) * NW + t] = s[r];
        }
    }
}

// pre-pass: per (l,unit) stable-sort the 16 (idx,w) slots by bank group
// (idx%8), apply lane-staggered cyclic phase, emit byte offsets + packed
// (w,w) f16 weights. Commutative dot -> semantics unchanged.
__global__ __launch_bounds__(256)
void prepass_kernel(const float* __restrict__ weights,
                    const int* __restrict__ edge_idx,
                    int* __restrict__ idxb,
                    unsigned* __restrict__ wpk)
{
    const int u = blockIdx.x * 256 + threadIdx.x;   // 0..2047 = l*NW + unit
    if (u >= NL * NW) return;
    const int base = u * NK;

    int   idx[NK];
    float w[NK];
    for (int k = 0; k < NK; ++k) {
        idx[k] = edge_idx[base + k];
        w[k]   = weights[base + k];
    }
    // stable insertion sort by group = idx & 7
    for (int i = 1; i < NK; ++i) {
        const int vi = idx[i]; const float vw = w[i];
        const int gi = vi & 7;
        int j = i - 1;
        while (j >= 0 && (idx[j] & 7) > gi) {
            idx[j + 1] = idx[j]; w[j + 1] = w[j]; --j;
        }
        idx[j + 1] = vi; w[j + 1] = vw;
    }
    // lane-in-wave stagger: spreads 16 consecutive lanes over all 16 phases
    const int lane  = u & 63;
    const int phase = ((lane & 7) << 1) | ((lane >> 3) & 1);
    for (int s = 0; s < NK; ++s) {
        const int k = (s + phase) & (NK - 1);
        idxb[base + s] = idx[k] << 4;
        wpk[base + s]  = pk16(w[k], w[k]);
    }
}

extern "C" void kernel_launch(void* const* d_in, const int* in_sizes, int n_in,
                              void* d_out, int out_size, void* d_ws, size_t ws_size,
                              hipStream_t stream)
{
    const float* inputs   = (const float*)d_in[0];
    const float* weights  = (const float*)d_in[1];
    const float* biases   = (const float*)d_in[2];
    const int*   edge_idx = (const int*)d_in[3];
    float* out = (float*)d_out;

    dim3 grid(NB / RPB);   // 4096
    dim3 block(NW);        // 256

    const size_t need = (size_t)NPARAM * 4 * 2;     // 256 KB
    if (ws_size >= need) {
        int*      idxb = (int*)d_ws;
        unsigned* wpk  = (unsigned*)((char*)d_ws + (size_t)NPARAM * 4);
        prepass_kernel<<<(NL * NW + 255) / 256, 256, 0, stream>>>(
            weights, edge_idx, idxb, wpk);
        ffn_gather_kernel<true><<<grid, block, 0, stream>>>(
            inputs, weights, biases, edge_idx, idxb, wpk, out);
    } else {
        ffn_gather_kernel<false><<<grid, block, 0, stream>>>(
            inputs, weights, biases, edge_idx, nullptr, nullptr, out);
    }
}